// Round 7
// baseline (1025.457 us; speedup 1.0000x reference)
//
#include <hip/hip_runtime.h>
#include <hip/hip_bf16.h>

typedef __hip_bfloat16 bf16;
#define DEV __device__ __forceinline__

// storage-dtype-generic accessors (F32 ? fp32 : bf16)
template<bool F32> DEV float LDX(const void* p, size_t i) {
  return F32 ? ((const float*)p)[i] : __bfloat162float(((const bf16*)p)[i]);
}
template<bool F32> DEV void STX(void* p, size_t i, float v) {
  if (F32) ((float*)p)[i] = v; else ((bf16*)p)[i] = __float2bfloat16(v);
}

DEV float wsum64(float v) {
  v += __shfl_xor(v, 1, 64);
  v += __shfl_xor(v, 2, 64);
  v += __shfl_xor(v, 4, 64);
  v += __shfl_xor(v, 8, 64);
  v += __shfl_xor(v, 16, 64);
  v += __shfl_xor(v, 32, 64);
  return v;
}

// Fold W_de/W_m through per-head column-sums of Wpd/Wpm.
// fold layout per layer l (stride 128 floats): [0..63] A_de[16][4],
// [64..95] A_m[8][4], [96..99] c[4]
__global__ __launch_bounds__(64) void fold_kernel(
    const float* __restrict__ W_de, const float* __restrict__ b_de,
    const float* __restrict__ W_m,  const float* __restrict__ b_m,
    const float* __restrict__ Wpd,  const float* __restrict__ bpd,
    const float* __restrict__ Wpm,  const float* __restrict__ bpm,
    float* __restrict__ fold)
{
  __shared__ float spd[64][4], spm[64][4];
  int t = threadIdx.x; // 0..63
  for (int l = 0; l < 2; ++l) {
    const float* wpd = Wpd + l * 4096;
    const float* wpm = Wpm + l * 4096;
    for (int hh = 0; hh < 4; ++hh) {
      float sd = 0.f, sm = 0.f;
      for (int hd = 0; hd < 16; ++hd) {
        sd += wpd[t * 64 + hh * 16 + hd];
        sm += wpm[t * 64 + hh * 16 + hd];
      }
      spd[t][hh] = sd; spm[t][hh] = sm;
    }
    __syncthreads();
    { // A_de[16][4]
      int i = t >> 2, hh = t & 3;
      float a = 0.f;
      for (int k = 0; k < 64; ++k) a += W_de[i * 64 + k] * spd[k][hh];
      fold[l * 128 + i * 4 + hh] = a;
    }
    if (t < 32) { // A_m[8][4]
      int i = t >> 2, hh = t & 3;
      float a = 0.f;
      for (int k = 0; k < 64; ++k) a += W_m[i * 64 + k] * spm[k][hh];
      fold[l * 128 + 64 + i * 4 + hh] = a;
    }
    if (t < 4) { // c[4] (zero in practice: all biases are zeros)
      int hh = t;
      float a = 0.f;
      for (int k = 0; k < 64; ++k)
        a += b_de[k] * spd[k][hh] + b_m[k] * spm[k][hh];
      for (int hd = 0; hd < 16; ++hd)
        a += bpd[l * 64 + hh * 16 + hd] + bpm[l * 64 + hh * 16 + hd];
      fold[l * 128 + 96 + hh] = a;
    }
    __syncthreads();
  }
}

// dst is sorted: CSR offsets via binary search, no atomics.
__global__ __launch_bounds__(256) void rowptr_kernel(
    const int* __restrict__ dst, int E, int N, int* __restrict__ rp)
{
  int n = blockIdx.x * blockDim.x + threadIdx.x;
  if (n > N) return;
  int lo = 0, hi = E;
  while (lo < hi) {
    int mid = (lo + hi) >> 1;
    if (dst[mid] < n) lo = mid + 1; else hi = mid;
  }
  rp[n] = lo;
}

// h = x@W_h + pe@W_pe + b_pe ; one wave per row, lane = output col
template<bool H32>
__global__ __launch_bounds__(256) void hinit_kernel(
    const float* __restrict__ x, const float* __restrict__ pe,
    const float* __restrict__ W_h, const float* __restrict__ W_pe,
    const float* __restrict__ b_pe, void* __restrict__ H, int N)
{
  int w = blockIdx.x * 4 + (threadIdx.x >> 6);
  if (w >= N) return;
  int lane = threadIdx.x & 63;
  float x0 = x[(size_t)w * 128 + lane];
  float x1 = x[(size_t)w * 128 + 64 + lane];
  float pr = pe[(size_t)w * 16 + (lane & 15)];
  float acc = b_pe[lane];
  #pragma unroll 8
  for (int i = 0; i < 64; ++i) acc += __shfl(x0, i, 64) * W_h[i * 64 + lane];
  #pragma unroll 8
  for (int i = 0; i < 64; ++i) acc += __shfl(x1, i, 64) * W_h[(64 + i) * 64 + lane];
  #pragma unroll
  for (int i = 0; i < 16; ++i) acc += __shfl(pr, i, 64) * W_pe[i * 64 + lane];
  STX<H32>(H, (size_t)w * 64 + lane, acc);
}

// K,V = h@W + b for layer l; one wave per row
template<bool H32, bool KV32>
__global__ __launch_bounds__(256) void kv_kernel(
    const void* __restrict__ H,
    const float* __restrict__ Wk, const float* __restrict__ bk,
    const float* __restrict__ Wv, const float* __restrict__ bv,
    void* __restrict__ K, void* __restrict__ V, int N, int l)
{
  int w = blockIdx.x * 4 + (threadIdx.x >> 6);
  if (w >= N) return;
  int lane = threadIdx.x & 63;
  const float* wk = Wk + l * 4096;
  const float* wv = Wv + l * 4096;
  float h = LDX<H32>(H, (size_t)w * 64 + lane);
  float ka = bk[l * 64 + lane];
  float va = bv[l * 64 + lane];
  #pragma unroll 8
  for (int k = 0; k < 64; ++k) {
    float hk = __shfl(h, k, 64);
    ka += hk * wk[k * 64 + lane];
    va += hk * wv[k * 64 + lane];
  }
  size_t o = (size_t)w * 64 + lane;
  STX<KV32>(K, o, ka);
  STX<KV32>(V, o, va);
}

// Fused per-layer: Q row matvec -> attention edge loop -> Wpi/WO/LN/FFN/LN.
// One wave per destination node; lane = head*16 + hd = output col.
template<bool H32, bool KV32>
__global__ __launch_bounds__(256) void layer_kernel(
    void* __restrict__ H, const void* __restrict__ K, const void* __restrict__ V,
    const int* __restrict__ src, const int* __restrict__ rp,
    const float* __restrict__ de, const float* __restrict__ m,
    const float* __restrict__ fold,
    const float* __restrict__ Wq, const float* __restrict__ bq,
    const float* __restrict__ I, const float* __restrict__ Wpi, const float* __restrict__ bpi,
    const float* __restrict__ WO, const float* __restrict__ bO,
    const float* __restrict__ g1, const float* __restrict__ b1,
    const float* __restrict__ Wf1, const float* __restrict__ bf1,
    const float* __restrict__ Wf2, const float* __restrict__ bf2,
    const float* __restrict__ g2, const float* __restrict__ b2,
    int N, int l)
{
  constexpr float BN_S = 0.9999950000374997f; // 1/sqrt(1+1e-5)
  int w = blockIdx.x * 4 + (threadIdx.x >> 6);
  if (w >= N) return;
  int lane = threadIdx.x & 63;
  int hh = lane >> 4, hd = lane & 15;

  float h = LDX<H32>(H, (size_t)w * 64 + lane); // residual h_in1

  // Q row = h@Wq + bq
  const float* wq = Wq + l * 4096;
  float q = bq[l * 64 + lane];
  #pragma unroll 8
  for (int k = 0; k < 64; ++k) q += __shfl(h, k, 64) * wq[k * 64 + lane];

  // attention over incoming edges
  const float* f = fold + l * 128;
  float a_de = f[hd * 4 + hh];
  float a_m = (hd < 8) ? f[64 + hd * 4 + hh] : 0.f;
  float c = f[96 + hh];
  float acc = 0.f, z = 0.f;
  int e0 = rp[w], e1 = rp[w + 1];
  for (int e = e0; e < e1; ++e) {
    int s = src[e];
    float kk = LDX<KV32>(K, (size_t)s * 64 + lane);
    float vv = LDX<KV32>(V, (size_t)s * 64 + lane);
    // score = 16*(dot*SCALE) + sum(pd) + sum(pm) = 4*dot + folded terms
    float t = 4.f * kk * q + de[(size_t)e * 16 + hd] * a_de;
    if (hd < 8) t += m[(size_t)e * 8 + hd] * a_m;
    t += __shfl_xor(t, 1, 64);
    t += __shfl_xor(t, 2, 64);
    t += __shfl_xor(t, 4, 64);
    t += __shfl_xor(t, 8, 64);
    float sv = expf(fminf(fmaxf(t + c, -5.f), 5.f));
    acc += sv * vv;
    z += sv;
  }
  float attn = acc / (z + 1e-10f);

  // u = attn + I@Wpi + bpi
  float Ir = I[(size_t)w * 16 + (lane & 15)];
  float u = attn + bpi[l * 64 + lane];
  const float* wpi = Wpi + l * 1024;
  #pragma unroll
  for (int i = 0; i < 16; ++i) u += __shfl(Ir, i, 64) * wpi[i * 64 + lane];

  // v = u@WO + bO ; h1 = LN(h + v)*BN_S
  const float* wo = WO + l * 4096;
  float v = bO[l * 64 + lane];
  #pragma unroll 8
  for (int k = 0; k < 64; ++k) v += __shfl(u, k, 64) * wo[k * 64 + lane];
  float hw = h + v;
  float mu = wsum64(hw) * (1.f / 64.f);
  float d = hw - mu;
  float var = wsum64(d * d) * (1.f / 64.f);
  float rs = 1.f / sqrtf(var + 1e-5f);
  float h1 = (d * rs * g1[l * 64 + lane] + b1[l * 64 + lane]) * BN_S;

  // FFN: relu(h1@Wf1+bf1)@Wf2+bf2
  const float* wf1 = Wf1 + l * 8192;
  float t0 = bf1[l * 128 + lane];
  float t1 = bf1[l * 128 + 64 + lane];
  #pragma unroll 4
  for (int k = 0; k < 64; ++k) {
    float hk = __shfl(h1, k, 64);
    t0 += hk * wf1[k * 128 + lane];
    t1 += hk * wf1[k * 128 + 64 + lane];
  }
  t0 = fmaxf(t0, 0.f);
  t1 = fmaxf(t1, 0.f);
  const float* wf2 = Wf2 + l * 8192;
  float y = bf2[l * 64 + lane];
  #pragma unroll 8
  for (int j = 0; j < 64; ++j) y += __shfl(t0, j, 64) * wf2[j * 64 + lane];
  #pragma unroll 8
  for (int j = 0; j < 64; ++j) y += __shfl(t1, j, 64) * wf2[(64 + j) * 64 + lane];
  float w2 = h1 + y;
  float mu2 = wsum64(w2) * (1.f / 64.f);
  float d2 = w2 - mu2;
  float var2 = wsum64(d2 * d2) * (1.f / 64.f);
  float rs2 = 1.f / sqrtf(var2 + 1e-5f);
  float h2 = (d2 * rs2 * g2[l * 64 + lane] + b2[l * 64 + lane]) * BN_S;
  STX<H32>(H, (size_t)w * 64 + lane, h2);
}

// out0 = h (fp32); x_hat = selu(h@Wr1+br1)@Wr2+br2 (fp32)
template<bool H32>
__global__ __launch_bounds__(256) void readout_kernel(
    const void* __restrict__ H,
    const float* __restrict__ Wr1, const float* __restrict__ br1,
    const float* __restrict__ Wr2, const float* __restrict__ br2,
    float* __restrict__ out, int N)
{
  int w = blockIdx.x * 4 + (threadIdx.x >> 6);
  if (w >= N) return;
  int lane = threadIdx.x & 63;
  float h = LDX<H32>(H, (size_t)w * 64 + lane);
  out[(size_t)w * 64 + lane] = h;
  int j = lane & 15;
  float md = br1[j];
  #pragma unroll 8
  for (int k = 0; k < 64; ++k) md += __shfl(h, k, 64) * Wr1[k * 16 + j];
  const float SC = 1.0507009873554805f, AL = 1.6732632423543772f;
  md = (md > 0.f) ? SC * md : SC * AL * expm1f(md);
  float x0 = br2[lane];
  float x1 = br2[64 + lane];
  #pragma unroll
  for (int jj = 0; jj < 16; ++jj) {
    float mj = __shfl(md, jj, 64);
    x0 += mj * Wr2[jj * 128 + lane];
    x1 += mj * Wr2[jj * 128 + 64 + lane];
  }
  size_t base = (size_t)N * 64 + (size_t)w * 128;
  out[base + lane] = x0;
  out[base + 64 + lane] = x1;
}

extern "C" void kernel_launch(void* const* d_in, const int* in_sizes, int n_in,
                              void* d_out, int out_size, void* d_ws, size_t ws_size,
                              hipStream_t stream)
{
  const int* src    = (const int*)d_in[0];
  const int* dst    = (const int*)d_in[1];
  const float* x    = (const float*)d_in[2];
  const float* pe   = (const float*)d_in[3];
  const float* de   = (const float*)d_in[4];
  const float* m    = (const float*)d_in[5];
  const float* I    = (const float*)d_in[6];
  const float* W_h  = (const float*)d_in[7];
  const float* W_pe = (const float*)d_in[8];
  const float* b_pe = (const float*)d_in[9];
  const float* W_de = (const float*)d_in[10];
  const float* b_de = (const float*)d_in[11];
  const float* W_m  = (const float*)d_in[12];
  const float* b_m  = (const float*)d_in[13];
  const float* Wq   = (const float*)d_in[14];
  const float* bq   = (const float*)d_in[15];
  const float* Wk   = (const float*)d_in[16];
  const float* bk   = (const float*)d_in[17];
  const float* Wv   = (const float*)d_in[18];
  const float* bv   = (const float*)d_in[19];
  const float* Wpd  = (const float*)d_in[20];
  const float* bpd  = (const float*)d_in[21];
  const float* Wpm  = (const float*)d_in[22];
  const float* bpm  = (const float*)d_in[23];
  const float* WO   = (const float*)d_in[24];
  const float* bO   = (const float*)d_in[25];
  const float* Wpi  = (const float*)d_in[26];
  const float* bpi  = (const float*)d_in[27];
  const float* g1   = (const float*)d_in[28];
  const float* b1   = (const float*)d_in[29];
  const float* g2   = (const float*)d_in[30];
  const float* b2   = (const float*)d_in[31];
  const float* Wf1  = (const float*)d_in[32];
  const float* bf1  = (const float*)d_in[33];
  const float* Wf2  = (const float*)d_in[34];
  const float* bf2  = (const float*)d_in[35];
  const float* Wr1  = (const float*)d_in[36];
  const float* br1  = (const float*)d_in[37];
  const float* Wr2  = (const float*)d_in[38];
  const float* br2  = (const float*)d_in[39];

  const int E = in_sizes[0];
  const int N = in_sizes[2] / 128;
  const size_t b64 = (size_t)N * 64;

  // ws layout: row_ptr | fold | H | [K | V] — ALL scratch in d_ws (d_out is
  // written only as final output; its poison machinery must not touch scratch).
  char* ws = (char*)d_ws;
  int* row_ptr = (int*)ws;
  size_t rp_bytes = (((size_t)(N + 1) * 4) + 255) & ~(size_t)255;
  float* fold = (float*)(ws + rp_bytes);
  char* buf = ws + rp_bytes + 1024;
  size_t base = rp_bytes + 1024;
  float* out = (float*)d_out;

  void *Hp, *Kp, *Vp;
  int tier;
  if (ws_size >= base + 3 * b64 * 4) {            // T1: H,K,V fp32
    tier = 1; Hp = buf; Kp = buf + b64 * 4; Vp = buf + 2 * b64 * 4;
  } else if (ws_size >= base + b64 * 4 + 2 * b64 * 2) { // T2: H fp32, K/V bf16
    tier = 2; Hp = buf; Kp = buf + b64 * 4; Vp = buf + b64 * 4 + b64 * 2;
  } else if (ws_size >= base + 3 * b64 * 2) {     // T3: all bf16
    tier = 3; Hp = buf; Kp = buf + b64 * 2; Vp = buf + 2 * b64 * 2;
  } else {                                        // T4: H,K bf16 ws; V bf16 in d_out
    tier = 4; Hp = buf; Kp = buf + b64 * 2; Vp = (void*)(out + b64);
  }

  int nb = (N + 3) / 4; // 4 waves (rows/nodes) per 256-thread block

  fold_kernel<<<1, 64, 0, stream>>>(W_de, b_de, W_m, b_m, Wpd, bpd, Wpm, bpm, fold);
  rowptr_kernel<<<(N + 256) / 256, 256, 0, stream>>>(dst, E, N, row_ptr);

  if (tier == 1) {
    hinit_kernel<true><<<nb, 256, 0, stream>>>(x, pe, W_h, W_pe, b_pe, Hp, N);
    for (int l = 0; l < 2; ++l) {
      kv_kernel<true, true><<<nb, 256, 0, stream>>>(Hp, Wk, bk, Wv, bv, Kp, Vp, N, l);
      layer_kernel<true, true><<<nb, 256, 0, stream>>>(Hp, Kp, Vp, src, row_ptr, de, m, fold,
          Wq, bq, I, Wpi, bpi, WO, bO, g1, b1, Wf1, bf1, Wf2, bf2, g2, b2, N, l);
    }
    readout_kernel<true><<<nb, 256, 0, stream>>>(Hp, Wr1, br1, Wr2, br2, out, N);
  } else if (tier == 2) {
    hinit_kernel<true><<<nb, 256, 0, stream>>>(x, pe, W_h, W_pe, b_pe, Hp, N);
    for (int l = 0; l < 2; ++l) {
      kv_kernel<true, false><<<nb, 256, 0, stream>>>(Hp, Wk, bk, Wv, bv, Kp, Vp, N, l);
      layer_kernel<true, false><<<nb, 256, 0, stream>>>(Hp, Kp, Vp, src, row_ptr, de, m, fold,
          Wq, bq, I, Wpi, bpi, WO, bO, g1, b1, Wf1, bf1, Wf2, bf2, g2, b2, N, l);
    }
    readout_kernel<true><<<nb, 256, 0, stream>>>(Hp, Wr1, br1, Wr2, br2, out, N);
  } else { // tier 3 and 4 share dtypes (all bf16)
    hinit_kernel<false><<<nb, 256, 0, stream>>>(x, pe, W_h, W_pe, b_pe, Hp, N);
    for (int l = 0; l < 2; ++l) {
      kv_kernel<false, false><<<nb, 256, 0, stream>>>(Hp, Wk, bk, Wv, bv, Kp, Vp, N, l);
      layer_kernel<false, false><<<nb, 256, 0, stream>>>(Hp, Kp, Vp, src, row_ptr, de, m, fold,
          Wq, bq, I, Wpi, bpi, WO, bO, g1, b1, Wf1, bf1, Wf2, bf2, g2, b2, N, l);
    }
    readout_kernel<false><<<nb, 256, 0, stream>>>(Hp, Wr1, br1, Wr2, br2, out, N);
  }
}